// Round 1
// baseline (682.427 us; speedup 1.0000x reference)
//
#include <hip/hip_runtime.h>
#include <cstdint>
#include <cstddef>

#define NS 512
#define NT 384
#define CM 64
#define CC 32
#define CZ 128

typedef __bf16 bf16x8 __attribute__((ext_vector_type(8)));
typedef float floatx4 __attribute__((ext_vector_type(4)));

// ---------------------------------------------------------------------------
// prep: WoutT[e][cd] = bf16(Wout[cd][e])   (128 x 1024)
// ---------------------------------------------------------------------------
__global__ __launch_bounds__(256) void prep_wout(const float* __restrict__ Wout,
                                                 __bf16* __restrict__ WT) {
  const int idx = blockIdx.x * 256 + threadIdx.x;  // 131072 total
  const int e = idx >> 10, cd = idx & 1023;
  WT[(size_t)e * 1024 + cd] = (__bf16)Wout[(size_t)cd * CZ + e];
}

// ---------------------------------------------------------------------------
// prep: rnorm[i][j] = 1 / (sum_s mask[s,i]*mask[s,j] + 0.001)
// ---------------------------------------------------------------------------
__global__ __launch_bounds__(128) void prep_norm(const float* __restrict__ mask,
                                                 float* __restrict__ rnorm) {
  __shared__ float mi[8][512];
  const int i0 = blockIdx.x * 8;
  for (int idx = threadIdx.x; idx < 8 * 512; idx += 128) {
    const int ii = idx >> 9, s = idx & 511;
    mi[ii][s] = mask[(size_t)s * NT + i0 + ii];
  }
  __syncthreads();
  for (int j = threadIdx.x; j < NT; j += 128) {
    float acc[8] = {0.f, 0.f, 0.f, 0.f, 0.f, 0.f, 0.f, 0.f};
    for (int s = 0; s < NS; ++s) {
      const float mj = mask[(size_t)s * NT + j];
#pragma unroll
      for (int ii = 0; ii < 8; ++ii) acc[ii] += mi[ii][s] * mj;
    }
#pragma unroll
    for (int ii = 0; ii < 8; ++ii)
      rnorm[(size_t)(i0 + ii) * NT + j] = 1.0f / (acc[ii] + 0.001f);
  }
}

// ---------------------------------------------------------------------------
// LN over c_m + projections a = (m@Wa)*mask, b = (m@Wb)*mask.
// Writes K-major bf16: Abf[(i*32+c)*512 + s], Bbf[(j*32+d)*512 + s].
// One wave per (i, 64-s-chunk): LDS transpose so lane = s-row, then per-lane
// serial LN + 2x (64x32) dot with wave-uniform (scalar-cached) weights.
// ---------------------------------------------------------------------------
__global__ __launch_bounds__(64) void ln_proj(const float* __restrict__ feat,
                                              const float* __restrict__ mask,
                                              const float* __restrict__ gamma,
                                              const float* __restrict__ beta,
                                              const float* __restrict__ Wa,
                                              const float* __restrict__ Wb,
                                              __bf16* __restrict__ Abf,
                                              __bf16* __restrict__ Bbf) {
  __shared__ float tile[64][65];  // +1 pad: conflict-free transpose
  const int bid = blockIdx.x;     // 384*8 = 3072
  const int i = bid >> 3;
  const int s0 = (bid & 7) << 6;
  const int lane = threadIdx.x;   // 0..63

#pragma unroll 8
  for (int r = 0; r < 64; ++r)
    tile[r][lane] = feat[((size_t)(s0 + r) * NT + i) * CM + lane];
  __syncthreads();

  float x[64];
#pragma unroll
  for (int k = 0; k < 64; ++k) x[k] = tile[lane][k];  // lane = s-row now

  float mu = 0.f;
#pragma unroll
  for (int k = 0; k < 64; ++k) mu += x[k];
  mu *= (1.0f / 64.0f);
  float var = 0.f;
#pragma unroll
  for (int k = 0; k < 64; ++k) { const float d = x[k] - mu; var += d * d; }
  var *= (1.0f / 64.0f);
  const float rstd = rsqrtf(var + 1e-5f);
#pragma unroll
  for (int k = 0; k < 64; ++k)
    x[k] = (x[k] - mu) * rstd * gamma[k] + beta[k];

  const float mv = mask[(size_t)(s0 + lane) * NT + i];

  float acc[32];
#pragma unroll
  for (int c = 0; c < 32; ++c) acc[c] = 0.f;
#pragma unroll 8
  for (int k = 0; k < 64; ++k) {
    const float mk = x[k];
#pragma unroll
    for (int c = 0; c < 32; ++c) acc[c] = fmaf(mk, Wa[k * 32 + c], acc[c]);
  }
#pragma unroll
  for (int c = 0; c < 32; ++c)
    Abf[(size_t)(i * 32 + c) * (size_t)NS + s0 + lane] = (__bf16)(acc[c] * mv);

#pragma unroll
  for (int c = 0; c < 32; ++c) acc[c] = 0.f;
#pragma unroll 8
  for (int k = 0; k < 64; ++k) {
    const float mk = x[k];
#pragma unroll
    for (int c = 0; c < 32; ++c) acc[c] = fmaf(mk, Wb[k * 32 + c], acc[c]);
  }
#pragma unroll
  for (int c = 0; c < 32; ++c)
    Bbf[(size_t)(i * 32 + c) * (size_t)NS + s0 + lane] = (__bf16)(acc[c] * mv);
}

// ---------------------------------------------------------------------------
// Fused: ab-tile GEMM (M=N=12288, K=512, 128x128 tile) + (ab @ WoutT) + bias
// + norm. 256 threads = 4 waves in 2x2, 4x4 16x16x32 bf16 MFMA frags/wave.
// ---------------------------------------------------------------------------
__global__ __launch_bounds__(256) void opm_gemm(const __bf16* __restrict__ A,
                                                const __bf16* __restrict__ B,
                                                const __bf16* __restrict__ WT,
                                                const float* __restrict__ bout,
                                                const float* __restrict__ rnorm,
                                                float* __restrict__ out) {
  __shared__ __align__(16) __bf16 As[128 * 32];
  __shared__ __align__(16) __bf16 Bs[128 * 32];
  __shared__ __align__(16) __bf16 P[16][1032];  // 16 pairs x 1024 cd (+8 pad)

  const int t = threadIdx.x;
  const int lane = t & 63;
  const int wid = t >> 6;
  const int wm = wid >> 1, wn = wid & 1;
  const int l15 = lane & 15, l4 = lane >> 4;
  const int bn = blockIdx.x, bm = blockIdx.y;

  const int srow = lane >> 2;          // row within 16-row staging region
  const int schunk = (lane & 3) * 8;   // bf16 offset of 16B chunk in k-dim

  floatx4 acc[4][4];
#pragma unroll
  for (int a = 0; a < 4; ++a)
#pragma unroll
    for (int b = 0; b < 4; ++b) acc[a][b] = (floatx4){0.f, 0.f, 0.f, 0.f};

  for (int kt = 0; kt < 16; ++kt) {
    __syncthreads();
#pragma unroll
    for (int c2 = 0; c2 < 2; ++c2) {
      const int region = c2 * 4 + wid;       // 0..7, 16 rows each
      const int row = region * 16 + srow;    // 0..127
      const __bf16* ga = A + (size_t)(bm * 128 + row) * (size_t)NS + kt * 32 + schunk;
      const __bf16* gb = B + (size_t)(bn * 128 + row) * (size_t)NS + kt * 32 + schunk;
      __builtin_amdgcn_global_load_lds(
          (const __attribute__((address_space(1))) void*)ga,
          (__attribute__((address_space(3))) void*)(As + region * 512), 16, 0, 0);
      __builtin_amdgcn_global_load_lds(
          (const __attribute__((address_space(1))) void*)gb,
          (__attribute__((address_space(3))) void*)(Bs + region * 512), 16, 0, 0);
    }
    __syncthreads();

    bf16x8 af[4], bfr[4];
#pragma unroll
    for (int tm = 0; tm < 4; ++tm)
      af[tm] = *(const bf16x8*)(As + (wm * 64 + tm * 16 + l15) * 32 + l4 * 8);
#pragma unroll
    for (int tn = 0; tn < 4; ++tn)
      bfr[tn] = *(const bf16x8*)(Bs + (wn * 64 + tn * 16 + l15) * 32 + l4 * 8);
#pragma unroll
    for (int tm = 0; tm < 4; ++tm)
#pragma unroll
      for (int tn = 0; tn < 4; ++tn)
        acc[tm][tn] = __builtin_amdgcn_mfma_f32_16x16x32_bf16(
            af[tm], bfr[tn], acc[tm][tn], 0, 0, 0);
  }

  // Scatter ab tile into pair-major bf16 P[p][c*32+d].
  // C/D frag mapping (verified m89/m91): col = lane&15, row = (lane>>4)*4+reg.
#pragma unroll
  for (int tm = 0; tm < 4; ++tm)
#pragma unroll
    for (int tn = 0; tn < 4; ++tn) {
      const int colbase = wn * 64 + tn * 16 + l15;
      const int j_l = colbase >> 5, d = colbase & 31;
#pragma unroll
      for (int r = 0; r < 4; ++r) {
        const int row = wm * 64 + tm * 16 + l4 * 4 + r;
        const int i_l = row >> 5, c = row & 31;
        P[i_l * 4 + j_l][c * 32 + d] = (__bf16)acc[tm][tn][r];
      }
    }
  __syncthreads();

  // Second GEMM: z[p][e] = sum_cd P[p][cd] * WoutT[e][cd]; M=16, N=128, K=1024.
  floatx4 acc2[2];
  acc2[0] = (floatx4){0.f, 0.f, 0.f, 0.f};
  acc2[1] = (floatx4){0.f, 0.f, 0.f, 0.f};
#pragma unroll 4
  for (int ks = 0; ks < 32; ++ks) {
    const bf16x8 pa = *(const bf16x8*)(&P[l15][ks * 32 + l4 * 8]);
#pragma unroll
    for (int tt = 0; tt < 2; ++tt) {
      const int n = (wid * 2 + tt) * 16 + l15;  // output channel e
      const bf16x8 wb = *(const bf16x8*)(WT + (size_t)n * 1024 + ks * 32 + l4 * 8);
      acc2[tt] = __builtin_amdgcn_mfma_f32_16x16x32_bf16(pa, wb, acc2[tt], 0, 0, 0);
    }
  }

  // Epilogue: out[i][j][e] = (z + bout[e]) * rnorm[i][j]
  float rn[4];
#pragma unroll
  for (int r = 0; r < 4; ++r) {
    const int p = l4 * 4 + r;
    const int i = bm * 4 + (p >> 2), j = bn * 4 + (p & 3);
    rn[r] = rnorm[(size_t)i * NT + j];
  }
#pragma unroll
  for (int tt = 0; tt < 2; ++tt) {
    const int e = (wid * 2 + tt) * 16 + l15;
    const float be = bout[e];
#pragma unroll
    for (int r = 0; r < 4; ++r) {
      const int p = l4 * 4 + r;
      const int i = bm * 4 + (p >> 2), j = bn * 4 + (p & 3);
      out[((size_t)i * NT + j) * CZ + e] = (acc2[tt][r] + be) * rn[r];
    }
  }
}

// ---------------------------------------------------------------------------
extern "C" void kernel_launch(void* const* d_in, const int* in_sizes, int n_in,
                              void* d_out, int out_size, void* d_ws, size_t ws_size,
                              hipStream_t stream) {
  const float* feat  = (const float*)d_in[0];  // [512,384,64]
  const float* mask  = (const float*)d_in[1];  // [512,384]
  const float* gamma = (const float*)d_in[2];  // [64]
  const float* beta  = (const float*)d_in[3];  // [64]
  const float* Wa    = (const float*)d_in[4];  // [64,32]
  const float* Wb    = (const float*)d_in[5];  // [64,32]
  const float* Wout  = (const float*)d_in[6];  // [1024,128]
  const float* bout  = (const float*)d_in[7];  // [128]
  float* out = (float*)d_out;                  // [384,384,128]

  char* ws = (char*)d_ws;
  const size_t AB_BYTES = (size_t)NT * CC * NS * sizeof(__bf16);  // 12,582,912
  __bf16* Abf = (__bf16*)(ws);
  __bf16* Bbf = (__bf16*)(ws + AB_BYTES);
  __bf16* WT  = (__bf16*)(ws + 2 * AB_BYTES);
  float* rnorm = (float*)(ws + 2 * AB_BYTES + (size_t)CZ * 1024 * sizeof(__bf16));
  // total workspace use: ~25.4 MB

  prep_wout<<<512, 256, 0, stream>>>(Wout, WT);
  prep_norm<<<48, 128, 0, stream>>>(mask, rnorm);
  ln_proj<<<NT * (NS / 64), 64, 0, stream>>>(feat, mask, gamma, beta, Wa, Wb, Abf, Bbf);
  opm_gemm<<<dim3(96, 96), 256, 0, stream>>>(Abf, Bbf, WT, bout, rnorm, out);
}

// Round 2
// 509.918 us; speedup vs baseline: 1.3383x; 1.3383x over previous
//
#include <hip/hip_runtime.h>
#include <cstdint>
#include <cstddef>

#define NS 512
#define NT 384
#define CM 64
#define CZ 128

typedef __bf16 bf16x8 __attribute__((ext_vector_type(8)));
typedef float floatx4 __attribute__((ext_vector_type(4)));
typedef float floatx16 __attribute__((ext_vector_type(16)));

// ---------------------------------------------------------------------------
// prep: WT[e][c*32+d] = bf16(Wout[(c*32+d)*128 + e])   (128 x 1024)
// ---------------------------------------------------------------------------
__global__ __launch_bounds__(256) void prep_wout(const float* __restrict__ Wout,
                                                 __bf16* __restrict__ WT) {
  const int idx = blockIdx.x * 256 + threadIdx.x;  // 131072 total
  const int e = idx >> 10, cd = idx & 1023;
  WT[(size_t)e * 1024 + cd] = (__bf16)Wout[(size_t)cd * CZ + e];
}

// ---------------------------------------------------------------------------
// prep: rnorm[i][j] = 1 / (sum_s mask[s,i]*mask[s,j] + 0.001). One block per i.
// ---------------------------------------------------------------------------
__global__ __launch_bounds__(256) void prep_norm(const float* __restrict__ mask,
                                                 float* __restrict__ rnorm) {
  __shared__ float mi[512];
  const int i = blockIdx.x, t = threadIdx.x;
  mi[t]       = mask[(size_t)t * NT + i];
  mi[t + 256] = mask[(size_t)(t + 256) * NT + i];
  __syncthreads();
  for (int j = t; j < NT; j += 256) {
    float acc = 0.f;
#pragma unroll 4
    for (int s = 0; s < NS; ++s) acc += mi[s] * mask[(size_t)s * NT + j];
    rnorm[(size_t)i * NT + j] = 1.0f / (acc + 0.001f);
  }
}

// ---------------------------------------------------------------------------
// LN over c_m + projections a=(m@Wa)*mask, b=(m@Wb)*mask. K-major bf16 out:
// Abf[(i*32+c)*512 + s]. One wave per (i, 64-s-chunk). float4 staging loads,
// stride-65 LDS transpose (b32 accesses: conflict-free).
// ---------------------------------------------------------------------------
__global__ __launch_bounds__(64) void ln_proj(const float* __restrict__ feat,
                                              const float* __restrict__ mask,
                                              const float* __restrict__ gamma,
                                              const float* __restrict__ beta,
                                              const float* __restrict__ Wa,
                                              const float* __restrict__ Wb,
                                              __bf16* __restrict__ Abf,
                                              __bf16* __restrict__ Bbf) {
  __shared__ float tile[64][65];
  const int bid = blockIdx.x;  // 3072
  const int i = bid >> 3;
  const int s0 = (bid & 7) << 6;
  const int lane = threadIdx.x;

  const int rsub = lane >> 4, cb = (lane & 15) * 4;
#pragma unroll
  for (int rr = 0; rr < 16; ++rr) {
    const int row = rr * 4 + rsub;
    const float4 v = *(const float4*)(feat + ((size_t)(s0 + row) * NT + i) * CM + cb);
    tile[row][cb] = v.x; tile[row][cb + 1] = v.y;
    tile[row][cb + 2] = v.z; tile[row][cb + 3] = v.w;
  }
  __syncthreads();

  float x[64];
#pragma unroll
  for (int k = 0; k < 64; ++k) x[k] = tile[lane][k];  // lane = s-row

  float mu = 0.f;
#pragma unroll
  for (int k = 0; k < 64; ++k) mu += x[k];
  mu *= (1.0f / 64.0f);
  float var = 0.f;
#pragma unroll
  for (int k = 0; k < 64; ++k) { const float d = x[k] - mu; var += d * d; }
  var *= (1.0f / 64.0f);
  const float rstd = rsqrtf(var + 1e-5f);
#pragma unroll
  for (int k = 0; k < 64; ++k)
    x[k] = (x[k] - mu) * rstd * gamma[k] + beta[k];

  const float mv = mask[(size_t)(s0 + lane) * NT + i];

  float acc[32];
#pragma unroll
  for (int c = 0; c < 32; ++c) acc[c] = 0.f;
#pragma unroll 8
  for (int k = 0; k < 64; ++k) {
    const float mk = x[k];
#pragma unroll
    for (int c = 0; c < 32; ++c) acc[c] = fmaf(mk, Wa[k * 32 + c], acc[c]);
  }
#pragma unroll
  for (int c = 0; c < 32; ++c)
    Abf[(size_t)(i * 32 + c) * (size_t)NS + s0 + lane] = (__bf16)(acc[c] * mv);

#pragma unroll
  for (int c = 0; c < 32; ++c) acc[c] = 0.f;
#pragma unroll 8
  for (int k = 0; k < 64; ++k) {
    const float mk = x[k];
#pragma unroll
    for (int c = 0; c < 32; ++c) acc[c] = fmaf(mk, Wb[k * 32 + c], acc[c]);
  }
#pragma unroll
  for (int c = 0; c < 32; ++c)
    Bbf[(size_t)(i * 32 + c) * (size_t)NS + s0 + lane] = (__bf16)(acc[c] * mv);
}

// ---------------------------------------------------------------------------
// Fused GEMM: block tile 128(m) x 256(n), K=512, 4 waves (2x2), wave tile
// 64x128 as 2x4 frags of 32x32x16 bf16 MFMA. XOR-swizzled LDS staging via
// global_load_lds. Epilogue: P (32 pairs x 1024 cd, bf16, aliased over As/Bs)
// -> second GEMM vs WT (M=32 pairs, N=128, K=1024, 32x32x16) + bias + norm.
// ---------------------------------------------------------------------------
__global__ __launch_bounds__(256, 2) void opm_gemm(const __bf16* __restrict__ A,
                                                   const __bf16* __restrict__ B,
                                                   const __bf16* __restrict__ WT,
                                                   const float* __restrict__ bout,
                                                   const float* __restrict__ rnorm,
                                                   float* __restrict__ out) {
  __shared__ __align__(16) char smem[66048];     // max(As+Bs=24KB, P=66048B)
  __bf16* As = (__bf16*)smem;                    // 128 rows x 32 k
  __bf16* Bs = (__bf16*)(smem + 8192);           // 256 rows x 32 k
  __bf16* P  = (__bf16*)smem;                    // 32 pairs x 1032 (aliased)

  const int t = threadIdx.x;
  const int lane = t & 63;
  const int wid = t >> 6;
  const int wm = wid & 1, wn = wid >> 1;         // wave grid 2(m) x 2(n)
  const int l31 = lane & 31, lh = lane >> 5;

  // supertile: 8(bm) x 4(bn) squares of 32 blocks for L2 locality
  const int sq = blockIdx.x >> 5, r5 = blockIdx.x & 31;
  const int bm = (sq % 12) * 8 + (r5 & 7);       // 0..95
  const int bn = (sq / 12) * 4 + (r5 >> 3);      // 0..47

  // staging: lane -> row (lane>>2) within 16-row region, chunk (lane&3);
  // fetch global chunk (lane&3)^((lane>>3)&3) so LDS holds XOR-swizzled tiles
  const int srow = lane >> 2;
  const int gch = ((lane & 3) ^ ((lane >> 3) & 3)) * 8;

  // frag read rows + their swizzle keys
  int rowA[2], rowB[4];
#pragma unroll
  for (int fm = 0; fm < 2; ++fm) rowA[fm] = wm * 64 + fm * 32 + l31;
#pragma unroll
  for (int fn = 0; fn < 4; ++fn) rowB[fn] = wn * 128 + fn * 32 + l31;

  floatx16 acc[2][4];
#pragma unroll
  for (int fm = 0; fm < 2; ++fm)
#pragma unroll
    for (int fn = 0; fn < 4; ++fn)
#pragma unroll
      for (int q = 0; q < 16; ++q) acc[fm][fn][q] = 0.f;

  for (int kt = 0; kt < 16; ++kt) {
    __syncthreads();
#pragma unroll
    for (int rg = wid; rg < 8; rg += 4) {        // A: 8 regions of 16 rows
      const __bf16* ga = A + (size_t)(bm * 128 + rg * 16 + srow) * NS + kt * 32 + gch;
      __builtin_amdgcn_global_load_lds(
          (const __attribute__((address_space(1))) void*)ga,
          (__attribute__((address_space(3))) void*)(As + rg * 512), 16, 0, 0);
    }
#pragma unroll
    for (int rg = wid; rg < 16; rg += 4) {       // B: 16 regions
      const __bf16* gb = B + (size_t)(bn * 256 + rg * 16 + srow) * NS + kt * 32 + gch;
      __builtin_amdgcn_global_load_lds(
          (const __attribute__((address_space(1))) void*)gb,
          (__attribute__((address_space(3))) void*)(Bs + rg * 512), 16, 0, 0);
    }
    __syncthreads();

#pragma unroll
    for (int ks = 0; ks < 2; ++ks) {
      const int ck = ks * 2 + lh;
      bf16x8 af[2], bf[4];
#pragma unroll
      for (int fm = 0; fm < 2; ++fm)
        af[fm] = *(const bf16x8*)(As + rowA[fm] * 32 + ((ck ^ ((rowA[fm] >> 1) & 3)) * 8));
#pragma unroll
      for (int fn = 0; fn < 4; ++fn)
        bf[fn] = *(const bf16x8*)(Bs + rowB[fn] * 32 + ((ck ^ ((rowB[fn] >> 1) & 3)) * 8));
#pragma unroll
      for (int fm = 0; fm < 2; ++fm)
#pragma unroll
        for (int fn = 0; fn < 4; ++fn)
          acc[fm][fn] = __builtin_amdgcn_mfma_f32_32x32x16_bf16(af[fm], bf[fn],
                                                                acc[fm][fn], 0, 0, 0);
    }
  }

  // Scatter ab tile -> P[p][c*32+d] bf16. 32x32 C/D: col=lane&31,
  // row=(reg&3)+8*(reg>>2)+4*(lane>>5)  [m74/m101].
  __syncthreads();
#pragma unroll
  for (int fm = 0; fm < 2; ++fm)
#pragma unroll
    for (int fn = 0; fn < 4; ++fn) {
      const int p = (wm * 2 + fm) * 8 + wn * 4 + fn;
      __bf16* Pp = P + p * 1032;
#pragma unroll
      for (int r = 0; r < 16; ++r) {
        const int c = (r & 3) + 8 * (r >> 2) + 4 * lh;
        Pp[c * 32 + l31] = (__bf16)acc[fm][fn][r];
      }
    }
  __syncthreads();

  // Second GEMM: z[p][e] = sum_cd P[p][cd]*WT[e][cd]; M=32 pairs, N=128, K=1024.
  // Wave covers e-range wid*32..+32. A-frag: lane row = p = l31, k = lh*8+j.
  floatx16 z;
#pragma unroll
  for (int q = 0; q < 16; ++q) z[q] = 0.f;
  const int e = wid * 32 + l31;
  const __bf16* wrow = WT + (size_t)e * 1024 + lh * 8;
  const __bf16* prow = P + l31 * 1032 + lh * 8;
#pragma unroll 4
  for (int ks = 0; ks < 64; ++ks) {
    const bf16x8 pa = *(const bf16x8*)(prow + ks * 16);
    const bf16x8 wb = *(const bf16x8*)(wrow + ks * 16);
    z = __builtin_amdgcn_mfma_f32_32x32x16_bf16(pa, wb, z, 0, 0, 0);
  }

  // Epilogue: out[i][j][e] = (z + bout[e]) * rnorm[i][j]
  const float be = bout[e];
#pragma unroll
  for (int r = 0; r < 16; ++r) {
    const int p = (r & 3) + 8 * (r >> 2) + 4 * lh;
    const int i = bm * 4 + (p >> 3), j = bn * 8 + (p & 7);
    const float rn = rnorm[(size_t)i * NT + j];
    out[((size_t)i * NT + j) * CZ + e] = (z[r] + be) * rn;
  }
}

// ---------------------------------------------------------------------------
extern "C" void kernel_launch(void* const* d_in, const int* in_sizes, int n_in,
                              void* d_out, int out_size, void* d_ws, size_t ws_size,
                              hipStream_t stream) {
  const float* feat  = (const float*)d_in[0];
  const float* mask  = (const float*)d_in[1];
  const float* gamma = (const float*)d_in[2];
  const float* beta  = (const float*)d_in[3];
  const float* Wa    = (const float*)d_in[4];
  const float* Wb    = (const float*)d_in[5];
  const float* Wout  = (const float*)d_in[6];
  const float* bout  = (const float*)d_in[7];
  float* out = (float*)d_out;

  char* ws = (char*)d_ws;
  const size_t AB_BYTES = (size_t)NT * 32 * NS * sizeof(__bf16);  // 12,582,912
  __bf16* Abf = (__bf16*)(ws);
  __bf16* Bbf = (__bf16*)(ws + AB_BYTES);
  __bf16* WT  = (__bf16*)(ws + 2 * AB_BYTES);
  float* rnorm = (float*)(ws + 2 * AB_BYTES + (size_t)CZ * 1024 * sizeof(__bf16));

  prep_wout<<<512, 256, 0, stream>>>(Wout, WT);
  prep_norm<<<NT, 256, 0, stream>>>(mask, rnorm);
  ln_proj<<<NT * (NS / 64), 64, 0, stream>>>(feat, mask, gamma, beta, Wa, Wb, Abf, Bbf);
  opm_gemm<<<96 * 48, 256, 0, stream>>>(Abf, Bbf, WT, bout, rnorm, out);
}

// Round 3
// 460.347 us; speedup vs baseline: 1.4824x; 1.1077x over previous
//
#include <hip/hip_runtime.h>
#include <cstdint>
#include <cstddef>

#define NS 512
#define NT 384
#define CZ 128

typedef __bf16 bf16x8 __attribute__((ext_vector_type(8)));
typedef __bf16 bf16x4 __attribute__((ext_vector_type(4)));
typedef float floatx16 __attribute__((ext_vector_type(16)));

// Workspace layouts (bf16 element units):
//   A_t[rb(96)][kc(64)][r(128)][e(8)]   panel = 65536 elems (128 rows, k=s)
//   B_t[pb(48)][kc(64)][r(256)][e(8)]   panel = 131072 elems
//   WT [e(128)][k(1024)]  k = (c>>4)*512 + d*16 + (c&15)
// k index = s;  kc = s>>3, e = s&7.  A-row m = i*32+c, B-row n = j*32+d.

// ---------------------------------------------------------------------------
__global__ __launch_bounds__(256) void prep_wout(const float* __restrict__ Wout,
                                                 __bf16* __restrict__ WT) {
  const int idx = blockIdx.x * 256 + threadIdx.x;  // 131072
  const int e = idx >> 10, kk = idx & 1023;
  const int round = kk >> 9, rem = kk & 511, d = rem >> 4, cp = rem & 15;
  const int c = round * 16 + cp;
  WT[idx] = (__bf16)Wout[(size_t)(c * 32 + d) * CZ + e];
}

// ---------------------------------------------------------------------------
__global__ __launch_bounds__(256) void prep_norm(const float* __restrict__ mask,
                                                 float* __restrict__ rnorm) {
  __shared__ float mi[512];
  const int i = blockIdx.x, t = threadIdx.x;
  mi[t]       = mask[(size_t)t * NT + i];
  mi[t + 256] = mask[(size_t)(t + 256) * NT + i];
  __syncthreads();
  for (int j = t; j < NT; j += 256) {
    float acc = 0.f;
#pragma unroll 4
    for (int s = 0; s < NS; ++s) acc += mi[s] * mask[(size_t)s * NT + j];
    rnorm[(size_t)i * NT + j] = 1.0f / (acc + 0.001f);
  }
}

// ---------------------------------------------------------------------------
// LN + projections, writing the tiled layouts. One wave per (i, 64-s chunk).
// ---------------------------------------------------------------------------
__global__ __launch_bounds__(64) void ln_proj(const float* __restrict__ feat,
                                              const float* __restrict__ mask,
                                              const float* __restrict__ gamma,
                                              const float* __restrict__ beta,
                                              const float* __restrict__ Wa,
                                              const float* __restrict__ Wb,
                                              __bf16* __restrict__ Abf,
                                              __bf16* __restrict__ Bbf) {
  __shared__ float tile[64][65];
  __shared__ __bf16 T[32 * 72];  // transpose buffer, row stride 72 (bank-safe)
  const int bid = blockIdx.x;    // 3072
  const int i = bid >> 3;
  const int s0 = (bid & 7) << 6;
  const int lane = threadIdx.x;
  const int l31 = lane & 31, lh = lane >> 5;

  const int rsub = lane >> 4, cb = (lane & 15) * 4;
#pragma unroll
  for (int rr = 0; rr < 16; ++rr) {
    const int row = rr * 4 + rsub;
    const float4 v = *(const float4*)(feat + ((size_t)(s0 + row) * NT + i) * 64 + cb);
    tile[row][cb] = v.x; tile[row][cb + 1] = v.y;
    tile[row][cb + 2] = v.z; tile[row][cb + 3] = v.w;
  }
  __syncthreads();

  float x[64];
#pragma unroll
  for (int k = 0; k < 64; ++k) x[k] = tile[lane][k];  // lane = s-row

  float mu = 0.f;
#pragma unroll
  for (int k = 0; k < 64; ++k) mu += x[k];
  mu *= (1.0f / 64.0f);
  float var = 0.f;
#pragma unroll
  for (int k = 0; k < 64; ++k) { const float d = x[k] - mu; var += d * d; }
  var *= (1.0f / 64.0f);
  const float rstd = rsqrtf(var + 1e-5f);
#pragma unroll
  for (int k = 0; k < 64; ++k)
    x[k] = (x[k] - mu) * rstd * gamma[k] + beta[k];

  const float mv = mask[(size_t)(s0 + lane) * NT + i];

  // ---- projection A ----
  float acc[32];
#pragma unroll
  for (int c = 0; c < 32; ++c) acc[c] = 0.f;
#pragma unroll 8
  for (int k = 0; k < 64; ++k) {
    const float mk = x[k];
#pragma unroll
    for (int c = 0; c < 32; ++c) acc[c] = fmaf(mk, Wa[k * 32 + c], acc[c]);
  }
#pragma unroll
  for (int c = 0; c < 32; ++c) T[c * 72 + lane] = (__bf16)(acc[c] * mv);
  __syncthreads();
  {
    // dest: rb=i>>2, r=(i&3)*32+c, kc = s0/8 + kc_loc, e = s&7
    __bf16* dst = Abf + (size_t)(i >> 2) * 65536 + (size_t)(s0 >> 3) * 1024 +
                  (size_t)((i & 3) * 32) * 8;
#pragma unroll
    for (int q = 0; q < 4; ++q) {
      const bf16x8 v = *(const bf16x8*)(T + l31 * 72 + (q * 2 + lh) * 8);
      *(bf16x8*)(dst + (size_t)(q * 2 + lh) * 1024 + l31 * 8) = v;
    }
  }
  __syncthreads();

  // ---- projection B ----
#pragma unroll
  for (int c = 0; c < 32; ++c) acc[c] = 0.f;
#pragma unroll 8
  for (int k = 0; k < 64; ++k) {
    const float mk = x[k];
#pragma unroll
    for (int c = 0; c < 32; ++c) acc[c] = fmaf(mk, Wb[k * 32 + c], acc[c]);
  }
#pragma unroll
  for (int c = 0; c < 32; ++c) T[c * 72 + lane] = (__bf16)(acc[c] * mv);
  __syncthreads();
  {
    __bf16* dst = Bbf + (size_t)(i >> 3) * 131072 + (size_t)(s0 >> 3) * 2048 +
                  (size_t)((i & 7) * 32) * 8;
#pragma unroll
    for (int q = 0; q < 4; ++q) {
      const bf16x8 v = *(const bf16x8*)(T + l31 * 72 + (q * 2 + lh) * 8);
      *(bf16x8*)(dst + (size_t)(q * 2 + lh) * 2048 + l31 * 8) = v;
    }
  }
}

// ---------------------------------------------------------------------------
// Fused GEMM. Block 128x256, 4 waves (2x2), wave 64x128 (2x4 frags 32x32x16).
// Double-buffered identity-copy staging (1 barrier/kt). Epilogue: 2 rounds
// over c-halves; P_half 32 pairs x 512 cd (d-major, padded); z accumulates.
// ---------------------------------------------------------------------------
__global__ __launch_bounds__(256) void opm_gemm(const __bf16* __restrict__ A,
                                                const __bf16* __restrict__ B,
                                                const __bf16* __restrict__ WT,
                                                const float* __restrict__ bout,
                                                const float* __restrict__ rnorm,
                                                float* __restrict__ out) {
  __shared__ __align__(16) __bf16 smem[24576];  // 49152 B
  // buffer b: As = smem + b*12288 (4 kc x 128 r x 8 e), Bs = As + 4096 (4x256x8)
  // P_half (epilogue alias): addr(p,d,c') = p*648 + d*20 + c'   (20736 elems)

  const int t = threadIdx.x, lane = t & 63, wid = t >> 6;
  const int wm = wid & 1, wn = wid >> 1;
  const int l31 = lane & 31, lh = lane >> 5;
  const int bm = blockIdx.x % 96, bn = blockIdx.x / 96;

  const __bf16* Apan = A + (size_t)bm * 65536;
  const __bf16* Bpan = B + (size_t)bn * 131072;

  floatx16 acc[2][4];
#pragma unroll
  for (int fm = 0; fm < 2; ++fm)
#pragma unroll
    for (int fn = 0; fn < 4; ++fn)
#pragma unroll
      for (int q = 0; q < 16; ++q) acc[fm][fn][q] = 0.f;

#define STAGE(kt, buf)                                                          \
  {                                                                             \
    __bf16* dst = smem + (buf) * 12288;                                         \
    _Pragma("unroll")                                                           \
    for (int g2 = 0; g2 < 2; ++g2) {                                            \
      const int g = wid * 2 + g2;                                               \
      __builtin_amdgcn_global_load_lds(                                         \
          (const __attribute__((address_space(1))) void*)(Apan + (kt) * 4096 +  \
                                                          g * 512 + lane * 8),  \
          (__attribute__((address_space(3))) void*)(dst + g * 512), 16, 0, 0);  \
    }                                                                           \
    _Pragma("unroll")                                                           \
    for (int g4 = 0; g4 < 4; ++g4) {                                            \
      const int g = wid * 4 + g4;                                               \
      __builtin_amdgcn_global_load_lds(                                         \
          (const __attribute__((address_space(1))) void*)(Bpan + (kt) * 8192 +  \
                                                          g * 512 + lane * 8),  \
          (__attribute__((address_space(3))) void*)(dst + 4096 + g * 512),      \
          16, 0, 0);                                                            \
    }                                                                           \
  }

  STAGE(0, 0);
  int buf = 0;
  for (int kt = 0; kt < 16; ++kt) {
    __syncthreads();                    // drains own stage loads of buf
    if (kt < 15) STAGE(kt + 1, buf ^ 1);
    const __bf16* As = smem + buf * 12288;
    const __bf16* Bs = As + 4096;
#pragma unroll
    for (int ks = 0; ks < 2; ++ks) {
      const int ck = ks * 2 + lh;
      bf16x8 af[2], bf[4];
#pragma unroll
      for (int fm = 0; fm < 2; ++fm)
        af[fm] = *(const bf16x8*)(As + ck * 1024 + (wm * 64 + fm * 32 + l31) * 8);
#pragma unroll
      for (int fn = 0; fn < 4; ++fn)
        bf[fn] = *(const bf16x8*)(Bs + ck * 2048 + (wn * 128 + fn * 32 + l31) * 8);
#pragma unroll
      for (int fm = 0; fm < 2; ++fm)
#pragma unroll
        for (int fn = 0; fn < 4; ++fn)
          acc[fm][fn] = __builtin_amdgcn_mfma_f32_32x32x16_bf16(af[fm], bf[fn],
                                                                acc[fm][fn], 0, 0, 0);
    }
    buf ^= 1;
  }
#undef STAGE

  // ---- epilogue: 2 rounds over c-halves ----
  floatx16 z;
#pragma unroll
  for (int q = 0; q < 16; ++q) z[q] = 0.f;
  const int e = wid * 32 + l31;

#pragma unroll
  for (int round = 0; round < 2; ++round) {
    __syncthreads();  // main-loop reads / previous GEMM2 reads complete
    // scatter regs r = round*8 + qp*4 + j  (c = 16*round + 8*qp + 4*lh + j)
#pragma unroll
    for (int fm = 0; fm < 2; ++fm)
#pragma unroll
      for (int fn = 0; fn < 4; ++fn) {
        const int p = (wm * 2 + fm) * 8 + wn * 4 + fn;
        __bf16* base = smem + p * 648 + l31 * 20 + lh * 4;
#pragma unroll
        for (int qp = 0; qp < 2; ++qp) {
          bf16x4 v;
#pragma unroll
          for (int j = 0; j < 4; ++j)
            v[j] = (__bf16)acc[fm][fn][round * 8 + qp * 4 + j];
          *(bf16x4*)(base + qp * 8) = v;
        }
      }
    __syncthreads();
    // GEMM2: z[p][e] += P_half[p][k] * WT[e][round*512 + k], K=512
    const __bf16* wrow = WT + (size_t)e * 1024 + round * 512 + lh * 8;
    const __bf16* prow = smem + l31 * 648 + lh * 8;
#pragma unroll 8
    for (int ks = 0; ks < 32; ++ks) {
      const bf16x8 pa = *(const bf16x8*)(prow + ks * 20);
      const bf16x8 wb = *(const bf16x8*)(wrow + ks * 16);
      z = __builtin_amdgcn_mfma_f32_32x32x16_bf16(pa, wb, z, 0, 0, 0);
    }
  }

  // out[i][j][e] = (z + bout[e]) * rnorm[i][j]
  const float be = bout[e];
#pragma unroll
  for (int r = 0; r < 16; ++r) {
    const int p = (r & 3) + 8 * (r >> 2) + 4 * lh;
    const int i = bm * 4 + (p >> 3), j = bn * 8 + (p & 7);
    const float rn = rnorm[(size_t)i * NT + j];
    out[((size_t)i * NT + j) * CZ + e] = (z[r] + be) * rn;
  }
}

// ---------------------------------------------------------------------------
extern "C" void kernel_launch(void* const* d_in, const int* in_sizes, int n_in,
                              void* d_out, int out_size, void* d_ws, size_t ws_size,
                              hipStream_t stream) {
  const float* feat  = (const float*)d_in[0];
  const float* mask  = (const float*)d_in[1];
  const float* gamma = (const float*)d_in[2];
  const float* beta  = (const float*)d_in[3];
  const float* Wa    = (const float*)d_in[4];
  const float* Wb    = (const float*)d_in[5];
  const float* Wout  = (const float*)d_in[6];
  const float* bout  = (const float*)d_in[7];
  float* out = (float*)d_out;

  char* ws = (char*)d_ws;
  const size_t AB_BYTES = (size_t)96 * 65536 * sizeof(__bf16);  // 12,582,912
  __bf16* Abf = (__bf16*)(ws);
  __bf16* Bbf = (__bf16*)(ws + AB_BYTES);
  __bf16* WT  = (__bf16*)(ws + 2 * AB_BYTES);
  float* rnorm = (float*)(ws + 2 * AB_BYTES + (size_t)CZ * 1024 * sizeof(__bf16));

  prep_wout<<<512, 256, 0, stream>>>(Wout, WT);
  prep_norm<<<NT, 256, 0, stream>>>(mask, rnorm);
  ln_proj<<<NT * (NS / 64), 64, 0, stream>>>(feat, mask, gamma, beta, Wa, Wb, Abf, Bbf);
  opm_gemm<<<96 * 48, 256, 0, stream>>>(Abf, Bbf, WT, bout, rnorm, out);
}